// Round 8
// baseline (167.730 us; speedup 1.0000x reference)
//
#include <hip/hip_runtime.h>
#include <math.h>

#define NPTS 40
#define NN   1600
#define WID  128

// stats layout (float offsets in stA): D/R/C indexed [i*40+a]
#define ST_D  0
#define ST_R  5120
#define ST_C  10240
#define ST_TR 15360
#define ST_T  15488

// coefficient matrices per hidden layer: 15 mats of [i*128+o]
#define CM_SZ1 16384

// accumulator layout (within ACC buffer)
#define PVA 0
#define PVB 40
#define PDG 80
#define A_SOFF 120
#define A_SDG  121
#define A_ISC  122

// workspace layout (float offsets)
#define WS_XTA   0
#define WS_XTB   204800
#define WS_STA   409600
#define WS_CM0   425984
#define WS_CM1   671744
#define WS_T1    917504
#define WS_ACC   917632
#define WS_PRAW  917760
#define WS_TOTAL 919360

static __device__ __forceinline__ float lrelu(float v) {
    return v >= 0.f ? v : 0.01f * v;
}

static __device__ __forceinline__ void pair_decode(int q, int& a, int& b) {
    int aa = 0, rem = q;
    while (rem >= 39 - aa) { rem -= 39 - aa; ++aa; }
    a = aa; b = aa + 1 + rem;
}

// ---------------- K1: layer0 (per-o block) + coef precompute + zeroing ----------------
__global__ __launch_bounds__(256) void k_l0c(
    const float* __restrict__ S, const float* __restrict__ W0, const float* __restrict__ b0,
    const float* __restrict__ Wh,
    float* __restrict__ XT, float* __restrict__ st,
    float* __restrict__ cm0, float* __restrict__ cm1,
    float* __restrict__ T1, float* __restrict__ accb)
{
    const int tid = threadIdx.x;
    const int o = blockIdx.x;

    if (o == 0) { // zero accumulators for this call (graph replay safe)
        if (tid < 128) T1[tid] = 0.f;
        if (tid >= 128) accb[tid - 128] = 0.f;
    }

    // ---- coefficient precompute (validated round-2 math; oo/ii mapping swapped
    //      so consecutive threads -> consecutive oo -> coalesced cm writes) ----
    {
        const int idx = o * 256 + tid;                // 0..32767
        const int l = idx >> 14;
        const int r2 = idx & 16383;
        const int oo = r2 & 127;                      // swapped: coalesced writes
        const int ii = (r2 >> 7) & 127;
        const float* w = Wh + ((l * WID + oo) * WID + ii) * 15;
        float* cm = l ? cm1 : cm0;
        const int base = ii * 128 + oo;
        const float w0=w[0],w1=w[1],w2=w[2],w3=w[3],w4=w[4],w5=w[5],w6=w[6],w7=w[7],
                    w8=w[8],w9=w[9],w10=w[10],w11=w[11],w12=w[12],w13=w[13],w14=w[14];
        cm[ 0*CM_SZ1+base] = w6 - w7 - w12 + w14;
        cm[ 1*CM_SZ1+base] = w8 - w10 - w11 + w14;
        cm[ 2*CM_SZ1+base] = w5 - w7 - w11 - w13 + 2.f*w14;
        cm[ 3*CM_SZ1+base] = w9 - w10 - w12 - w13 + 2.f*w14;
        cm[ 4*CM_SZ1+base] = w7 - w14;
        cm[ 5*CM_SZ1+base] = w10 - w14;
        cm[ 6*CM_SZ1+base] = w11 - w14;
        cm[ 7*CM_SZ1+base] = w12 - w14;
        cm[ 8*CM_SZ1+base] = w0 - w1 - w2 - w3 + 2.f*w4;
        cm[ 9*CM_SZ1+base] = w1 - w4;
        cm[10*CM_SZ1+base] = w2 - w4;
        cm[11*CM_SZ1+base] = w13 - w14;
        cm[12*CM_SZ1+base] = w14;
        cm[13*CM_SZ1+base] = w3 - w4;
        cm[14*CM_SZ1+base] = w4;
    }

    // ---- layer 0 (symmetric basis, 11 ops) — validated round-2 math ----
    __shared__ float sS[NPTS * 5];
    __shared__ float sX[NN];
    __shared__ float sP[NN];
    __shared__ float sR[NPTS], sC[NPTS], sD[NPTS], sTT[2];

    for (int t = tid; t < NPTS * 5; t += 256) sS[t] = S[t];
    __syncthreads();
    for (int p = tid; p < NN; p += 256) {
        int a = p / NPTS, b = p % NPTS;
        float acc = 0.f;
#pragma unroll
        for (int k = 0; k < 5; ++k) acc += sS[a * 5 + k] * sS[b * 5 + k];
        sX[p] = acc;
    }
    __syncthreads();
    if (tid < NPTS) {
        float r = 0.f, c = 0.f;
        for (int jj = 0; jj < NPTS; ++jj) { r += sX[tid * NPTS + jj]; c += sX[jj * NPTS + tid]; }
        sR[tid] = r; sC[tid] = c; sD[tid] = sX[tid * 41];
    }
    __syncthreads();
    if (tid == 0) {
        float tr = 0.f, T = 0.f;
        for (int a = 0; a < NPTS; ++a) { tr += sD[a]; T += sR[a]; }
        sTT[0] = tr; sTT[1] = T;
    }
    __syncthreads();

    float w[11];
#pragma unroll
    for (int k = 0; k < 11; ++k) w[k] = W0[o * 11 + k];
    const float tr = sTT[0], T = sTT[1];
    const float cfX = w[6] - w[7] - w[8] + w[10];
    const float cfd = w[5] - w[7] - w[8] - w[9] + 2.f * w[10];
    const float cfR = w[7] - w[10];
    const float cfC = w[8] - w[10];
    const float so  = w[9] * tr + w[10] * (T - tr) + b0[o * 2 + 1];
    const float cdd = w[0] - w[1] - w[2] - w[3] + 2.f * w[4];
    const float cdR = w[1] - w[4];
    const float cdC = w[2] - w[4];
    const float sd  = w[3] * tr + w[4] * (T - tr) + b0[o * 2 + 0];

    for (int p = tid; p < NN; p += 256) {
        int a = p / NPTS, b = p % NPTS;
        float v;
        if (a == b) {
            v = cdd * sD[a] + cdR * sR[a] + cdC * sC[a] + sd;
        } else {
            float xs = sX[p] + sX[b * NPTS + a];
            v = cfX * xs + cfd * (sD[a] + sD[b]) + cfR * (sR[a] + sR[b]) + cfC * (sC[a] + sC[b]) + so;
        }
        sP[p] = lrelu(v);
    }
    __syncthreads();
    for (int p = tid; p < NN; p += 256) XT[p * WID + o] = sP[p];
    if (tid < NPTS) {
        float r = 0.f, c = 0.f;
        for (int jj = 0; jj < NPTS; ++jj) { r += sP[tid * NPTS + jj]; c += sP[jj * NPTS + tid]; }
        st[ST_D + o * NPTS + tid] = sP[tid * 41];
        st[ST_R + o * NPTS + tid] = r;
        st[ST_C + o * NPTS + tid] = c;
        sR[tid] = r; sD[tid] = sP[tid * 41];
    }
    __syncthreads();
    if (tid == 0) {
        float t2 = 0.f, T2 = 0.f;
        for (int a = 0; a < NPTS; ++a) { t2 += sD[a]; T2 += sR[a]; }
        st[ST_TR + o] = t2; st[ST_T + o] = T2;
    }
}

// ---------------- K2: hidden layer 1 with inline vterms + T1 atomic (validated round-4) ----------------
__global__ __launch_bounds__(256) void k_hid1(
    const float* __restrict__ XTA, const float* __restrict__ stA,
    const float* __restrict__ cm, const float* __restrict__ bl,
    float* __restrict__ XTB, float* __restrict__ T1)
{
    const int tid = threadIdx.x, blk = blockIdx.x;
    const int j = tid >> 7, o = tid & 127;
    const bool diag = (blk < 40);
    int e0, e1, e2, e3;
    pair_decode(2 * blk, e0, e1);
    pair_decode(2 * blk + 1, e2, e3);
    const int epl[5] = { e0, e1, e2, e3, diag ? blk : 0 };
    const int nep = diag ? 5 : 4;

    __shared__ float sD[5][128], sR[5][128], sC[5][128], sTr[128], sT[128];
    __shared__ float sxab[2][128], sxba[2][128];
    __shared__ float vpart[11][2][128];
    __shared__ float svt[11][128];

    for (int t = tid; t < nep * 128; t += 256) {
        const int e = t >> 7, k = t & 127, a = epl[e];
        sD[e][k] = stA[ST_D + k * 40 + a];
        sR[e][k] = stA[ST_R + k * 40 + a];
        sC[e][k] = stA[ST_C + k * 40 + a];
    }
    if (tid < 128) { sTr[o] = stA[ST_TR + o]; sT[o] = stA[ST_T + o]; }
    {
        const int a = epl[2 * j], b = epl[2 * j + 1];
        sxab[j][o] = XTA[(a * 40 + b) * 128 + o];
        sxba[j][o] = XTA[(b * 40 + a) * 128 + o];
    }
    __syncthreads();

    // vterm accumulation: j splits the k range
    float fva0 = 0, fva1 = 0, fva2 = 0, fva3 = 0;
    float fvb0 = 0, fvb1 = 0, fvb2 = 0, fvb3 = 0;
    float fso = 0, fdg = 0, fsd = 0;
    const int k0 = 64 * j;
    for (int k = k0; k < k0 + 64; ++k) {
        const int c = k * 128 + o;
        const float m2 = cm[2*CM_SZ1+c], m3 = cm[3*CM_SZ1+c], m4 = cm[4*CM_SZ1+c],
                    m5 = cm[5*CM_SZ1+c], m6 = cm[6*CM_SZ1+c], m7 = cm[7*CM_SZ1+c];
        {
            const float d = sD[0][k], r = sR[0][k], cc = sC[0][k];
            fva0 += m2*d + m4*r + m6*cc; fvb0 += m3*d + m5*r + m7*cc;
        }
        {
            const float d = sD[1][k], r = sR[1][k], cc = sC[1][k];
            fva1 += m2*d + m4*r + m6*cc; fvb1 += m3*d + m5*r + m7*cc;
        }
        {
            const float d = sD[2][k], r = sR[2][k], cc = sC[2][k];
            fva2 += m2*d + m4*r + m6*cc; fvb2 += m3*d + m5*r + m7*cc;
        }
        {
            const float d = sD[3][k], r = sR[3][k], cc = sC[3][k];
            fva3 += m2*d + m4*r + m6*cc; fvb3 += m3*d + m5*r + m7*cc;
        }
        fso += cm[11*CM_SZ1+c] * sTr[k] + cm[12*CM_SZ1+c] * sT[k];
        if (diag) {
            fdg += cm[8*CM_SZ1+c]*sD[4][k] + cm[9*CM_SZ1+c]*sR[4][k] + cm[10*CM_SZ1+c]*sC[4][k];
            fsd += cm[13*CM_SZ1+c]*sTr[k] + cm[14*CM_SZ1+c]*sT[k];
        }
    }
    vpart[0][j][o]=fva0; vpart[1][j][o]=fva1; vpart[2][j][o]=fva2; vpart[3][j][o]=fva3;
    vpart[4][j][o]=fvb0; vpart[5][j][o]=fvb1; vpart[6][j][o]=fvb2; vpart[7][j][o]=fvb3;
    vpart[8][j][o]=fso; vpart[9][j][o]=fdg; vpart[10][j][o]=fsd;
    __syncthreads();
    if (tid < 128) {
        for (int m = 0; m < 8; ++m) svt[m][o] = vpart[m][0][o] + vpart[m][1][o];
        svt[8][o]  = vpart[8][0][o] + vpart[8][1][o] + bl[o * 2 + 1];
        svt[9][o]  = vpart[9][0][o] + vpart[9][1][o];
        svt[10][o] = vpart[10][0][o] + vpart[10][1][o] + bl[o * 2 + 0];
    }
    __syncthreads();

    // main contraction
    float acc1 = 0.f, acc2 = 0.f;
#pragma unroll 8
    for (int i = 0; i < 128; ++i) {
        const float c1v = cm[i * 128 + o];
        const float c2v = cm[CM_SZ1 + i * 128 + o];
        const float xab = sxab[j][i], xba = sxba[j][i];
        acc1 += c1v * xab + c2v * xba;
        acc2 += c1v * xba + c2v * xab;
    }
    const int a = epl[2 * j], b = epl[2 * j + 1];
    const float so = svt[8][o];
    const float o1 = lrelu(acc1 + svt[2 * j][o]     + svt[4 + 2 * j + 1][o] + so);
    const float o2 = lrelu(acc2 + svt[2 * j + 1][o] + svt[4 + 2 * j][o]     + so);
    XTB[(a * 40 + b) * 128 + o] = o1;
    XTB[(b * 40 + a) * 128 + o] = o2;
    float xd = 0.f;
    if (diag && j == 0) {
        xd = lrelu(svt[9][o] + svt[10][o]);
        XTB[(blk * 41) * 128 + o] = xd;
    }
    // T1 accumulation (one atomic per o per block)
    vpart[0][j][o] = o1 + o2 + xd;
    __syncthreads();
    if (tid < 128) atomicAdd(&T1[o], vpart[0][0][o] + vpart[0][1][o]);
}

// ---------------- K3: hidden layer 2 with inline vterms + pairs functionals (round-4 body, no fence/final) ----------------
__global__ __launch_bounds__(256) void k_hid2(
    const float* __restrict__ XTB, const float* __restrict__ T1,
    const float* __restrict__ cm, const float* __restrict__ bl,
    const float* __restrict__ Wp, const float* __restrict__ Wi,
    float* __restrict__ praw, float* __restrict__ accb)
{
    const int tid = threadIdx.x, blk = blockIdx.x;
    const int j = tid >> 7, o = tid & 127;
    const bool diag = (blk < 40);
    int e0, e1, e2, e3;
    pair_decode(2 * blk, e0, e1);
    pair_decode(2 * blk + 1, e2, e3);
    const int epl[5] = { e0, e1, e2, e3, diag ? blk : 0 };
    const int nep = diag ? 5 : 4;

    __shared__ float sD[5][128], sR[5][128], sC[5][128], sTr[128], sT[128];
    __shared__ float sxab[2][128], sxba[2][128];
    __shared__ float vpart[11][2][128];
    __shared__ float svt[11][128];
    __shared__ float sxd[128];
    __shared__ float rr[7][2][128];

    // ---- stats of XTB for needed endpoints (deterministic, redundant per block) ----
    {
        const int k = o, h = j;
        for (int e = 0; e < nep; ++e) {
            const int a = epl[e];
            float r = 0.f, c = 0.f;
            for (int b = 20 * h; b < 20 * h + 20; ++b) {
                r += XTB[(a * 40 + b) * 128 + k];
                c += XTB[(b * 40 + a) * 128 + k];
            }
            vpart[0][h][k] = r; vpart[1][h][k] = c;
            __syncthreads();
            if (tid < 128) {
                sD[e][k] = XTB[(a * 41) * 128 + k];
                sR[e][k] = vpart[0][0][k] + vpart[0][1][k];
                sC[e][k] = vpart[1][0][k] + vpart[1][1][k];
            }
            __syncthreads();
        }
        float t = 0.f;
        for (int a2 = 20 * h; a2 < 20 * h + 20; ++a2) t += XTB[(a2 * 41) * 128 + k];
        vpart[0][h][k] = t;
        __syncthreads();
        if (tid < 128) { sTr[k] = vpart[0][0][k] + vpart[0][1][k]; sT[k] = T1[k]; }
    }
    {
        const int a = epl[2 * j], b = epl[2 * j + 1];
        sxab[j][o] = XTB[(a * 40 + b) * 128 + o];
        sxba[j][o] = XTB[(b * 40 + a) * 128 + o];
    }
    __syncthreads();

    // ---- vterm accumulation (cm1) ----
    float fva0 = 0, fva1 = 0, fva2 = 0, fva3 = 0;
    float fvb0 = 0, fvb1 = 0, fvb2 = 0, fvb3 = 0;
    float fso = 0, fdg = 0, fsd = 0;
    const int k0 = 64 * j;
    for (int k = k0; k < k0 + 64; ++k) {
        const int c = k * 128 + o;
        const float m2 = cm[2*CM_SZ1+c], m3 = cm[3*CM_SZ1+c], m4 = cm[4*CM_SZ1+c],
                    m5 = cm[5*CM_SZ1+c], m6 = cm[6*CM_SZ1+c], m7 = cm[7*CM_SZ1+c];
        {
            const float d = sD[0][k], r = sR[0][k], cc = sC[0][k];
            fva0 += m2*d + m4*r + m6*cc; fvb0 += m3*d + m5*r + m7*cc;
        }
        {
            const float d = sD[1][k], r = sR[1][k], cc = sC[1][k];
            fva1 += m2*d + m4*r + m6*cc; fvb1 += m3*d + m5*r + m7*cc;
        }
        {
            const float d = sD[2][k], r = sR[2][k], cc = sC[2][k];
            fva2 += m2*d + m4*r + m6*cc; fvb2 += m3*d + m5*r + m7*cc;
        }
        {
            const float d = sD[3][k], r = sR[3][k], cc = sC[3][k];
            fva3 += m2*d + m4*r + m6*cc; fvb3 += m3*d + m5*r + m7*cc;
        }
        fso += cm[11*CM_SZ1+c] * sTr[k] + cm[12*CM_SZ1+c] * sT[k];
        if (diag) {
            fdg += cm[8*CM_SZ1+c]*sD[4][k] + cm[9*CM_SZ1+c]*sR[4][k] + cm[10*CM_SZ1+c]*sC[4][k];
            fsd += cm[13*CM_SZ1+c]*sTr[k] + cm[14*CM_SZ1+c]*sT[k];
        }
    }
    vpart[0][j][o]=fva0; vpart[1][j][o]=fva1; vpart[2][j][o]=fva2; vpart[3][j][o]=fva3;
    vpart[4][j][o]=fvb0; vpart[5][j][o]=fvb1; vpart[6][j][o]=fvb2; vpart[7][j][o]=fvb3;
    vpart[8][j][o]=fso; vpart[9][j][o]=fdg; vpart[10][j][o]=fsd;
    __syncthreads();
    if (tid < 128) {
        for (int m = 0; m < 8; ++m) svt[m][o] = vpart[m][0][o] + vpart[m][1][o];
        svt[8][o]  = vpart[8][0][o] + vpart[8][1][o] + bl[o * 2 + 1];
        svt[9][o]  = vpart[9][0][o] + vpart[9][1][o];
        svt[10][o] = vpart[10][0][o] + vpart[10][1][o] + bl[o * 2 + 0];
    }
    __syncthreads();

    // ---- main contraction -> x1, x2 (layer-2 outputs, never stored) ----
    float acc1 = 0.f, acc2 = 0.f;
#pragma unroll 8
    for (int i = 0; i < 128; ++i) {
        const float c1v = cm[i * 128 + o];
        const float c2v = cm[CM_SZ1 + i * 128 + o];
        const float xab = sxab[j][i], xba = sxba[j][i];
        acc1 += c1v * xab + c2v * xba;
        acc2 += c1v * xba + c2v * xab;
    }
    const int pa = epl[2 * j], pb = epl[2 * j + 1];
    const float so = svt[8][o];
    const float x1 = lrelu(acc1 + svt[2 * j][o]     + svt[4 + 2 * j + 1][o] + so);
    const float x2 = lrelu(acc2 + svt[2 * j + 1][o] + svt[4 + 2 * j][o]     + so);
    if (diag && j == 0) sxd[o] = lrelu(svt[9][o] + svt[10][o]);

    // ---- pairs-layer linear functionals of x1,x2 ----
    const float p0 = Wp[o*11+0], p1 = Wp[o*11+1], p2 = Wp[o*11+2], p3 = Wp[o*11+3],
                p4 = Wp[o*11+4], p5 = Wp[o*11+5], p6 = Wp[o*11+6], p7 = Wp[o*11+7],
                p8 = Wp[o*11+8], p9 = Wp[o*11+9], p10 = Wp[o*11+10];
    const float wi0 = Wi[o*2+0], wi1 = Wi[o*2+1];
    const float s12 = x1 + x2;
    rr[0][j][o] = (p6 - p7 - p8 + p10) * s12;  // praw
    rr[1][j][o] = (p7 - p10) * s12;            // -> pva[a], pva[b]
    rr[2][j][o] = (p8 - p10) * s12;            // -> pvb[a], pvb[b]
    rr[3][j][o] = (p5 - p9) * s12;             // -> pdg[a], pdg[b]
    rr[4][j][o] = p10 * s12;                   // -> psoff
    rr[5][j][o] = p9 * s12;                    // -> psdg
    rr[6][j][o] = wi1 * s12;                   // -> Isc
    __syncthreads();
    for (int stp = 64; stp > 0; stp >>= 1) {
        if (o < stp) {
            for (int m = 0; m < 7; ++m) rr[m][j][o] += rr[m][j][o + stp];
        }
        __syncthreads();
    }
    if (o == 0) {
        const float v = rr[0][j][0];
        praw[pa * 40 + pb] = v;
        praw[pb * 40 + pa] = v;
        atomicAdd(&accb[PVA + pa], rr[1][j][0]); atomicAdd(&accb[PVA + pb], rr[1][j][0]);
        atomicAdd(&accb[PVB + pa], rr[2][j][0]); atomicAdd(&accb[PVB + pb], rr[2][j][0]);
        atomicAdd(&accb[PDG + pa], rr[3][j][0]); atomicAdd(&accb[PDG + pb], rr[3][j][0]);
        atomicAdd(&accb[A_SOFF], rr[4][j][0]);
        atomicAdd(&accb[A_SDG],  rr[5][j][0]);
        atomicAdd(&accb[A_ISC],  rr[6][j][0]);
    }
    if (diag) {
        __syncthreads();
        const float xdv = (j == 0) ? sxd[o] : 0.f;
        rr[0][j][o] = (p1 - p4) * xdv;   // pva diag
        rr[1][j][o] = (p2 - p4) * xdv;   // pvb diag
        rr[2][j][o] = (p0 - p3) * xdv;   // pdg diag
        rr[3][j][o] = p4 * xdv;          // psoff diag
        rr[4][j][o] = p3 * xdv;          // psdg diag
        rr[5][j][o] = wi0 * xdv;         // Isc diag
        __syncthreads();
        for (int stp = 64; stp > 0; stp >>= 1) {
            if (o < stp) {
                for (int m = 0; m < 6; ++m) rr[m][j][o] += rr[m][j][o + stp];
            }
            __syncthreads();
        }
        if (tid == 0) {
            atomicAdd(&accb[PVA + blk], rr[0][0][0]);
            atomicAdd(&accb[PVB + blk], rr[1][0][0]);
            atomicAdd(&accb[PDG + blk], rr[2][0][0]);
            atomicAdd(&accb[A_SOFF], rr[3][0][0]);
            atomicAdd(&accb[A_SDG],  rr[4][0][0]);
            atomicAdd(&accb[A_ISC],  rr[5][0][0]);
        }
    }
}

// ---------------- K4: final (1 block) — validated round-2/4/5 math ----------------
__global__ __launch_bounds__(256) void k_final(
    const float* __restrict__ S, const float* __restrict__ praw,
    const float* __restrict__ acc, const float* __restrict__ bp,
    const float* __restrict__ bi, float* __restrict__ out)
{
    __shared__ float sm[2201];
    __shared__ double dbuf[55];
    const int tid = threadIdx.x;

    float* sPr = sm;          // 1600
    float* sSS = sm + 1600;   // 200
    float* M1  = sm + 1800;   // 200
    float* sA  = sm + 2000;   // 25

    for (int t = tid; t < NPTS * 5; t += 256) sSS[t] = S[t];
    const float psoff = acc[A_SOFF] + bp[1];
    const float psdg  = acc[A_SDG]  + bp[0];
    for (int p = tid; p < NN; p += 256) {
        const int a = p / NPTS, b = p % NPTS;
        float v;
        if (a == b) v = acc[PDG + a] + psdg;
        else        v = praw[p] + acc[PVA + a] + acc[PVB + b] + psoff;
        sPr[p] = v;
    }
    __syncthreads();
    if (tid < 200) {
        const int c = tid / NPTS, b = tid % NPTS;
        float s = 0.f;
        for (int a = 0; a < NPTS; ++a) s += sSS[a * 5 + c] * sPr[a * NPTS + b];
        M1[c * NPTS + b] = s;
    }
    __syncthreads();
    if (tid < 25) {
        const int c = tid / 5, d = tid % 5;
        float s = 0.f;
        for (int b = 0; b < NPTS; ++b) s += M1[c * NPTS + b] * sSS[b * 5 + d];
        sA[tid] = s;
    }
    __syncthreads();

    if (tid == 0) {
        const float isc = acc[A_ISC] + bi[0];
        double (*A)[5] = (double(*)[5])&dbuf[0];
        double (*V)[5] = (double(*)[5])&dbuf[25];
        for (int c = 0; c < 5; ++c)
            for (int d = 0; d < 5; ++d)
                A[c][d] = (double)((c >= d) ? sA[c * 5 + d] : sA[d * 5 + c]);
        for (int c = 0; c < 5; ++c) A[c][c] += (double)isc;
        for (int c = 0; c < 5; ++c)
            for (int d = 0; d < 5; ++d) V[c][d] = (c == d) ? 1.0 : 0.0;

        double dscale = 1.0;
        for (int c = 0; c < 5; ++c) dscale += A[c][c] * A[c][c];
        for (int sweep = 0; sweep < 30; ++sweep) {
            double off = 0.0;
            for (int p = 0; p < 4; ++p)
                for (int q = p + 1; q < 5; ++q) off += A[p][q] * A[p][q];
            if (off < 1e-26 * dscale) break;
            for (int p = 0; p < 4; ++p) {
                for (int q = p + 1; q < 5; ++q) {
                    const double apq = A[p][q];
                    if (fabs(apq) < 1e-300) continue;
                    const double theta = (A[q][q] - A[p][p]) / (2.0 * apq);
                    const double t = (theta >= 0.0 ? 1.0 : -1.0) / (fabs(theta) + sqrt(theta * theta + 1.0));
                    const double cth = 1.0 / sqrt(t * t + 1.0);
                    const double sth = t * cth;
                    for (int k = 0; k < 5; ++k) {
                        const double akp = A[k][p], akq = A[k][q];
                        A[k][p] = cth * akp - sth * akq;
                        A[k][q] = sth * akp + cth * akq;
                    }
                    for (int k = 0; k < 5; ++k) {
                        const double apk = A[p][k], aqk = A[q][k];
                        A[p][k] = cth * apk - sth * aqk;
                        A[q][k] = sth * apk + cth * aqk;
                    }
                    for (int k = 0; k < 5; ++k) {
                        const double vkp = V[k][p], vkq = V[k][q];
                        V[k][p] = cth * vkp - sth * vkq;
                        V[k][q] = sth * vkp + cth * vkq;
                    }
                }
            }
        }
        int best = 0;
        for (int k = 1; k < 5; ++k) if (A[k][k] > A[best][best]) best = k;
        double u[5];
        for (int k = 0; k < 5; ++k) u[k] = V[k][best];
        int jm = 0; double am = fabs(u[0]);
        for (int k = 1; k < 5; ++k) if (fabs(u[k]) > am) { am = fabs(u[k]); jm = k; }
        if (u[jm] < 0.0) for (int k = 0; k < 5; ++k) u[k] = -u[k];
        for (int k = 0; k < 5; ++k) dbuf[50 + k] = u[k];
    }
    __syncthreads();
    if (tid < NPTS) {
        float s = 0.f;
#pragma unroll
        for (int k = 0; k < 5; ++k) s += sSS[tid * 5 + k] * (float)dbuf[50 + k];
        out[tid] = s;
    }
}

extern "C" void kernel_launch(void* const* d_in, const int* in_sizes, int n_in,
                              void* d_out, int out_size, void* d_ws, size_t ws_size,
                              hipStream_t stream) {
    const float* S  = (const float*)d_in[0];
    // d_in[1..3] basis tensors: unused (structure derived analytically)
    const float* W0 = (const float*)d_in[4];
    const float* b0 = (const float*)d_in[5];
    const float* Wh = (const float*)d_in[6];
    const float* bh = (const float*)d_in[7];
    const float* Wp = (const float*)d_in[8];
    const float* bp = (const float*)d_in[9];
    const float* Wi = (const float*)d_in[10];
    const float* bi = (const float*)d_in[11];
    float* outf = (float*)d_out;
    float* ws = (float*)d_ws;
    if (ws_size < (size_t)WS_TOTAL * sizeof(float)) return;

    float* XTA  = ws + WS_XTA;
    float* XTB  = ws + WS_XTB;
    float* stA  = ws + WS_STA;
    float* cm0  = ws + WS_CM0;
    float* cm1  = ws + WS_CM1;
    float* T1   = ws + WS_T1;
    float* acc  = ws + WS_ACC;
    float* praw = ws + WS_PRAW;

    k_l0c<<<WID, 256, 0, stream>>>(S, W0, b0, Wh, XTA, stA, cm0, cm1, T1, acc);
    k_hid1<<<390, 256, 0, stream>>>(XTA, stA, cm0, bh, XTB, T1);
    k_hid2<<<390, 256, 0, stream>>>(XTB, T1, cm1, bh + 2 * WID, Wp, Wi, praw, acc);
    k_final<<<1, 256, 0, stream>>>(S, praw, acc, bp, bi, outf);
}

// Round 9
// 137.660 us; speedup vs baseline: 1.2184x; 1.2184x over previous
//
#include <hip/hip_runtime.h>
#include <math.h>

#define NPTS 40
#define NN   1600
#define WID  128

// stats layout (float offsets in stA): D/R/C indexed [i*40+a]
#define ST_D  0
#define ST_R  5120
#define ST_C  10240
#define ST_TR 15360
#define ST_T  15488

// vterm buffer layout: va/vb/vdg indexed [a*128+o]
#define VT_VA   0
#define VT_VB   5120
#define VT_VDG  10240
#define VT_SOFF 15360
#define VT_SDG  15488

// coefficient matrices per hidden layer: 15 mats of [i*128+o]
#define CM_SZ1 16384

// accumulator layout (within ACC buffer)
#define PVA 0
#define PVB 40
#define PDG 80
#define A_SOFF 120
#define A_SDG  121
#define A_ISC  122

// workspace layout (float offsets)
#define WS_XTA   0
#define WS_XTB   204800
#define WS_STA   409600
#define WS_CM0   425984
#define WS_CM1   671744
#define WS_VT1   917504
#define WS_VT2   933120
#define WS_PRAW  948736
#define WS_T1    950336
#define WS_ACC   950464
#define WS_TOTAL 950656

static __device__ __forceinline__ float lrelu(float v) {
    return v >= 0.f ? v : 0.01f * v;
}

static __device__ __forceinline__ void pair_decode(int q, int& a, int& b) {
    int aa = 0, rem = q;
    while (rem >= 39 - aa) { rem -= 39 - aa; ++aa; }
    a = aa; b = aa + 1 + rem;
}

// ---------------- K1: layer0 (per-o block) + coef precompute + zeroing ----------------
__global__ __launch_bounds__(256) void k_l0c(
    const float* __restrict__ S, const float* __restrict__ W0, const float* __restrict__ b0,
    const float* __restrict__ Wh,
    float* __restrict__ XT, float* __restrict__ st,
    float* __restrict__ cm0, float* __restrict__ cm1,
    float* __restrict__ T1, float* __restrict__ accb)
{
    const int tid = threadIdx.x;
    const int o = blockIdx.x;

    if (o == 0) { // zero accumulators for this call (graph replay safe)
        if (tid < 128) T1[tid] = 0.f;
        if (tid >= 128) accb[tid - 128] = 0.f;
    }

    // ---- coefficient precompute (validated round-8: coalesced writes) ----
    {
        const int idx = o * 256 + tid;                // 0..32767
        const int l = idx >> 14;
        const int r2 = idx & 16383;
        const int oo = r2 & 127;                      // coalesced cm writes
        const int ii = (r2 >> 7) & 127;
        const float* w = Wh + ((l * WID + oo) * WID + ii) * 15;
        float* cm = l ? cm1 : cm0;
        const int base = ii * 128 + oo;
        const float w0=w[0],w1=w[1],w2=w[2],w3=w[3],w4=w[4],w5=w[5],w6=w[6],w7=w[7],
                    w8=w[8],w9=w[9],w10=w[10],w11=w[11],w12=w[12],w13=w[13],w14=w[14];
        cm[ 0*CM_SZ1+base] = w6 - w7 - w12 + w14;
        cm[ 1*CM_SZ1+base] = w8 - w10 - w11 + w14;
        cm[ 2*CM_SZ1+base] = w5 - w7 - w11 - w13 + 2.f*w14;
        cm[ 3*CM_SZ1+base] = w9 - w10 - w12 - w13 + 2.f*w14;
        cm[ 4*CM_SZ1+base] = w7 - w14;
        cm[ 5*CM_SZ1+base] = w10 - w14;
        cm[ 6*CM_SZ1+base] = w11 - w14;
        cm[ 7*CM_SZ1+base] = w12 - w14;
        cm[ 8*CM_SZ1+base] = w0 - w1 - w2 - w3 + 2.f*w4;
        cm[ 9*CM_SZ1+base] = w1 - w4;
        cm[10*CM_SZ1+base] = w2 - w4;
        cm[11*CM_SZ1+base] = w13 - w14;
        cm[12*CM_SZ1+base] = w14;
        cm[13*CM_SZ1+base] = w3 - w4;
        cm[14*CM_SZ1+base] = w4;
    }

    // ---- layer 0 (symmetric basis, 11 ops) — validated round-2 math ----
    __shared__ float sS[NPTS * 5];
    __shared__ float sX[NN];
    __shared__ float sP[NN];
    __shared__ float sR[NPTS], sC[NPTS], sD[NPTS], sTT[2];

    for (int t = tid; t < NPTS * 5; t += 256) sS[t] = S[t];
    __syncthreads();
    for (int p = tid; p < NN; p += 256) {
        int a = p / NPTS, b = p % NPTS;
        float acc = 0.f;
#pragma unroll
        for (int k = 0; k < 5; ++k) acc += sS[a * 5 + k] * sS[b * 5 + k];
        sX[p] = acc;
    }
    __syncthreads();
    if (tid < NPTS) {
        float r = 0.f, c = 0.f;
        for (int jj = 0; jj < NPTS; ++jj) { r += sX[tid * NPTS + jj]; c += sX[jj * NPTS + tid]; }
        sR[tid] = r; sC[tid] = c; sD[tid] = sX[tid * 41];
    }
    __syncthreads();
    if (tid == 0) {
        float tr = 0.f, T = 0.f;
        for (int a = 0; a < NPTS; ++a) { tr += sD[a]; T += sR[a]; }
        sTT[0] = tr; sTT[1] = T;
    }
    __syncthreads();

    float w[11];
#pragma unroll
    for (int k = 0; k < 11; ++k) w[k] = W0[o * 11 + k];
    const float tr = sTT[0], T = sTT[1];
    const float cfX = w[6] - w[7] - w[8] + w[10];
    const float cfd = w[5] - w[7] - w[8] - w[9] + 2.f * w[10];
    const float cfR = w[7] - w[10];
    const float cfC = w[8] - w[10];
    const float so  = w[9] * tr + w[10] * (T - tr) + b0[o * 2 + 1];
    const float cdd = w[0] - w[1] - w[2] - w[3] + 2.f * w[4];
    const float cdR = w[1] - w[4];
    const float cdC = w[2] - w[4];
    const float sd  = w[3] * tr + w[4] * (T - tr) + b0[o * 2 + 0];

    for (int p = tid; p < NN; p += 256) {
        int a = p / NPTS, b = p % NPTS;
        float v;
        if (a == b) {
            v = cdd * sD[a] + cdR * sR[a] + cdC * sC[a] + sd;
        } else {
            float xs = sX[p] + sX[b * NPTS + a];
            v = cfX * xs + cfd * (sD[a] + sD[b]) + cfR * (sR[a] + sR[b]) + cfC * (sC[a] + sC[b]) + so;
        }
        sP[p] = lrelu(v);
    }
    __syncthreads();
    for (int p = tid; p < NN; p += 256) XT[p * WID + o] = sP[p];
    if (tid < NPTS) {
        float r = 0.f, c = 0.f;
        for (int jj = 0; jj < NPTS; ++jj) { r += sP[tid * NPTS + jj]; c += sP[jj * NPTS + tid]; }
        st[ST_D + o * NPTS + tid] = sP[tid * 41];
        st[ST_R + o * NPTS + tid] = r;
        st[ST_C + o * NPTS + tid] = c;
        sR[tid] = r; sD[tid] = sP[tid * 41];
    }
    __syncthreads();
    if (tid == 0) {
        float t2 = 0.f, T2 = 0.f;
        for (int a = 0; a < NPTS; ++a) { t2 += sD[a]; T2 += sR[a]; }
        st[ST_TR + o] = t2; st[ST_T + o] = T2;
    }
}

// ---------------- vterms for one hidden layer (validated round-5 math) ----------------
static __device__ void vterm_phase(int a, int tid, bool second,
    const float* __restrict__ XT, const float* __restrict__ stA,
    const float* __restrict__ T1,
    const float* __restrict__ cm, const float* __restrict__ bias,
    float* __restrict__ vt, float* sm)
{
    const int i = tid & 127, h = tid >> 7;
    float* sD  = sm;
    float* sR  = sm + 128;
    float* sC  = sm + 256;
    float* sTr = sm + 384;
    float* sT  = sm + 512;
    float* vp  = sm + 1024;   // up to 768

    if (a < 40) {
        if (!second) {
            if (tid < 128) {
                sD[i] = stA[ST_D + i * 40 + a];
                sR[i] = stA[ST_R + i * 40 + a];
                sC[i] = stA[ST_C + i * 40 + a];
            }
        } else {
            float r = 0.f, c = 0.f;
            for (int b = 20 * h; b < 20 * h + 20; ++b) {
                r += XT[(a * 40 + b) * WID + i];
                c += XT[(b * 40 + a) * WID + i];
            }
            vp[h * 128 + i] = r;
            vp[256 + h * 128 + i] = c;
            __syncthreads();
            if (tid < 128) {
                sR[i] = vp[i] + vp[128 + i];
                sC[i] = vp[256 + i] + vp[384 + i];
                sD[i] = XT[(a * 41) * WID + i];
            }
        }
        __syncthreads();
        const int o = i;
        float acca = 0.f, accb = 0.f, accg = 0.f;
        for (int k = 64 * h; k < 64 * h + 64; ++k) {
            const int c = k * 128 + o;
            const float d = sD[k], r = sR[k], cc = sC[k];
            acca += cm[ 2*CM_SZ1+c]*d + cm[ 4*CM_SZ1+c]*r + cm[ 6*CM_SZ1+c]*cc;
            accb += cm[ 3*CM_SZ1+c]*d + cm[ 5*CM_SZ1+c]*r + cm[ 7*CM_SZ1+c]*cc;
            accg += cm[ 8*CM_SZ1+c]*d + cm[ 9*CM_SZ1+c]*r + cm[10*CM_SZ1+c]*cc;
        }
        __syncthreads();
        vp[h * 128 + o] = acca; vp[256 + h * 128 + o] = accb; vp[512 + h * 128 + o] = accg;
        __syncthreads();
        if (tid < 128) {
            vt[VT_VA  + a * 128 + o] = vp[o] + vp[128 + o];
            vt[VT_VB  + a * 128 + o] = vp[256 + o] + vp[384 + o];
            vt[VT_VDG + a * 128 + o] = vp[512 + o] + vp[640 + o];
        }
    } else {
        if (!second) {
            if (tid < 128) { sTr[i] = stA[ST_TR + i]; sT[i] = stA[ST_T + i]; }
        } else {
            if (tid < 128) {
                float trv = 0.f;
                for (int a2 = 0; a2 < 40; ++a2) trv += XT[(a2 * 41) * WID + i];
                sTr[i] = trv; sT[i] = T1[i];
            }
        }
        __syncthreads();
        const int o = i;
        float soff = 0.f, sdg = 0.f;
        for (int k = 64 * h; k < 64 * h + 64; ++k) {
            const int c = k * 128 + o;
            soff += cm[11*CM_SZ1+c] * sTr[k] + cm[12*CM_SZ1+c] * sT[k];
            sdg  += cm[13*CM_SZ1+c] * sTr[k] + cm[14*CM_SZ1+c] * sT[k];
        }
        vp[h * 128 + o] = soff; vp[256 + h * 128 + o] = sdg;
        __syncthreads();
        if (tid < 128) {
            vt[VT_SOFF + o] = vp[o] + vp[128 + o] + bias[o * 2 + 1];
            vt[VT_SDG  + o] = vp[256 + o] + vp[384 + o] + bias[o * 2 + 0];
        }
    }
}

// ---------------- K2: vt1 (41 blocks) ----------------
__global__ __launch_bounds__(256) void k_sv1(
    const float* __restrict__ stA, const float* __restrict__ cm,
    const float* __restrict__ bias, float* __restrict__ vt)
{
    __shared__ float sm[2048];
    vterm_phase(blockIdx.x, threadIdx.x, false, nullptr, stA, nullptr, cm, bias, vt, sm);
}

// ---------------- K4: vt2 (41 blocks) ----------------
__global__ __launch_bounds__(256) void k_sv2(
    const float* __restrict__ XTB, const float* __restrict__ T1,
    const float* __restrict__ cm, const float* __restrict__ bias, float* __restrict__ vt)
{
    __shared__ float sm[2048];
    vterm_phase(blockIdx.x, threadIdx.x, true, XTB, nullptr, T1, cm, bias, vt, sm);
}

// ---------------- K3: hidden layer 1 (390 blocks) + T1 atomic ----------------
__global__ __launch_bounds__(256) void k_hid1(
    const float* __restrict__ XTA, const float* __restrict__ vt1,
    const float* __restrict__ cm0, float* __restrict__ XTB, float* __restrict__ T1)
{
    const int tid = threadIdx.x, slot = blockIdx.x;
    const int j = tid >> 7, o = tid & 127;
    int aa, bb; pair_decode(2 * slot + j, aa, bb);

    __shared__ float sm[1536];
    float* sxab = sm; float* sxba = sm + 256; float* rrT = sm + 512;

    sxab[j*128 + o] = XTA[(aa * 40 + bb) * WID + o];
    sxba[j*128 + o] = XTA[(bb * 40 + aa) * WID + o];
    __syncthreads();
    float a1 = 0.f, a2 = 0.f;
#pragma unroll 8
    for (int i2 = 0; i2 < 128; ++i2) {
        const float c1v = cm0[i2 * 128 + o];
        const float c2v = cm0[CM_SZ1 + i2 * 128 + o];
        const float xab = sxab[j*128 + i2], xba = sxba[j*128 + i2];
        a1 += c1v * xab + c2v * xba;
        a2 += c1v * xba + c2v * xab;
    }
    const float so = vt1[VT_SOFF + o];
    const float o1 = lrelu(a1 + vt1[VT_VA + aa*128 + o] + vt1[VT_VB + bb*128 + o] + so);
    const float o2 = lrelu(a2 + vt1[VT_VA + bb*128 + o] + vt1[VT_VB + aa*128 + o] + so);
    XTB[(aa * 40 + bb) * WID + o] = o1;
    XTB[(bb * 40 + aa) * WID + o] = o2;
    float xd = 0.f;
    if (slot < 40 && j == 0) {
        xd = lrelu(vt1[VT_VDG + slot*128 + o] + vt1[VT_SDG + o]);
        XTB[(slot * 41) * WID + o] = xd;
    }
    rrT[j*128 + o] = o1 + o2 + xd;
    __syncthreads();
    if (tid < 128) atomicAdd(&T1[o], rrT[o] + rrT[128 + o]);
}

// ---------------- K5: hidden layer 2 + pairs functionals (no fence, no final) ----------------
__global__ __launch_bounds__(256) void k_hid2(
    const float* __restrict__ XTB, const float* __restrict__ vt2,
    const float* __restrict__ cm1,
    const float* __restrict__ Wp, const float* __restrict__ Wi,
    float* __restrict__ praw, float* __restrict__ acc)
{
    const int tid = threadIdx.x, slot = blockIdx.x;
    const int j = tid >> 7, o = tid & 127;
    int aa, bb; pair_decode(2 * slot + j, aa, bb);

    __shared__ float sm[2816];
    float* sxab = sm; float* sxba = sm + 256; float* rr = sm + 1024;

    sxab[j*128 + o] = XTB[(aa * 40 + bb) * WID + o];
    sxba[j*128 + o] = XTB[(bb * 40 + aa) * WID + o];
    __syncthreads();
    float a1 = 0.f, a2 = 0.f;
#pragma unroll 8
    for (int i2 = 0; i2 < 128; ++i2) {
        const float c1v = cm1[i2 * 128 + o];
        const float c2v = cm1[CM_SZ1 + i2 * 128 + o];
        const float xab = sxab[j*128 + i2], xba = sxba[j*128 + i2];
        a1 += c1v * xab + c2v * xba;
        a2 += c1v * xba + c2v * xab;
    }
    const float so2 = vt2[VT_SOFF + o];
    const float x1 = lrelu(a1 + vt2[VT_VA + aa*128 + o] + vt2[VT_VB + bb*128 + o] + so2);
    const float x2 = lrelu(a2 + vt2[VT_VA + bb*128 + o] + vt2[VT_VB + aa*128 + o] + so2);

    const float p5 = Wp[o*11+5], p6 = Wp[o*11+6], p7 = Wp[o*11+7],
                p8 = Wp[o*11+8], p9 = Wp[o*11+9], p10 = Wp[o*11+10];
    const float wi1 = Wi[o*2+1];
    const float s12 = x1 + x2;
    rr[0*256 + j*128 + o] = (p6 - p7 - p8 + p10) * s12;
    rr[1*256 + j*128 + o] = (p7 - p10) * s12;
    rr[2*256 + j*128 + o] = (p8 - p10) * s12;
    rr[3*256 + j*128 + o] = (p5 - p9) * s12;
    rr[4*256 + j*128 + o] = p10 * s12;
    rr[5*256 + j*128 + o] = p9 * s12;
    rr[6*256 + j*128 + o] = wi1 * s12;
    __syncthreads();
    for (int stp = 64; stp > 0; stp >>= 1) {
        if (o < stp)
            for (int m = 0; m < 7; ++m)
                rr[m*256 + j*128 + o] += rr[m*256 + j*128 + o + stp];
        __syncthreads();
    }
    if (o == 0) {
        const float v = rr[0*256 + j*128];
        praw[aa * 40 + bb] = v;
        praw[bb * 40 + aa] = v;
        atomicAdd(&acc[PVA + aa], rr[1*256 + j*128]); atomicAdd(&acc[PVA + bb], rr[1*256 + j*128]);
        atomicAdd(&acc[PVB + aa], rr[2*256 + j*128]); atomicAdd(&acc[PVB + bb], rr[2*256 + j*128]);
        atomicAdd(&acc[PDG + aa], rr[3*256 + j*128]); atomicAdd(&acc[PDG + bb], rr[3*256 + j*128]);
        atomicAdd(&acc[A_SOFF], rr[4*256 + j*128]);
        atomicAdd(&acc[A_SDG],  rr[5*256 + j*128]);
        atomicAdd(&acc[A_ISC],  rr[6*256 + j*128]);
    }

    if (slot < 40) { // diagonal contributions (validated round-5 math)
        __syncthreads();
        float xdv = 0.f;
        if (j == 0) xdv = lrelu(vt2[VT_VDG + slot * 128 + o] + vt2[VT_SDG + o]);
        const float p0 = Wp[o*11+0], p1 = Wp[o*11+1], p2 = Wp[o*11+2],
                    p3 = Wp[o*11+3], p4 = Wp[o*11+4];
        const float wi0 = Wi[o*2+0];
        rr[0*256 + j*128 + o] = (p1 - p4) * xdv;
        rr[1*256 + j*128 + o] = (p2 - p4) * xdv;
        rr[2*256 + j*128 + o] = (p0 - p3) * xdv;
        rr[3*256 + j*128 + o] = p4 * xdv;
        rr[4*256 + j*128 + o] = p3 * xdv;
        rr[5*256 + j*128 + o] = wi0 * xdv;
        __syncthreads();
        for (int stp = 64; stp > 0; stp >>= 1) {
            if (o < stp)
                for (int m = 0; m < 6; ++m)
                    rr[m*256 + j*128 + o] += rr[m*256 + j*128 + o + stp];
            __syncthreads();
        }
        if (tid == 0) {
            atomicAdd(&acc[PVA + slot], rr[0*256] + rr[0*256+128]);
            atomicAdd(&acc[PVB + slot], rr[1*256] + rr[1*256+128]);
            atomicAdd(&acc[PDG + slot], rr[2*256] + rr[2*256+128]);
            atomicAdd(&acc[A_SOFF], rr[3*256] + rr[3*256+128]);
            atomicAdd(&acc[A_SDG],  rr[4*256] + rr[4*256+128]);
            atomicAdd(&acc[A_ISC],  rr[5*256] + rr[5*256+128]);
        }
    }
}

// ---------------- K6: final (1 block) — A assembly validated; Jacobi now fp32 ----------------
__global__ __launch_bounds__(256) void k_final(
    const float* __restrict__ S, const float* __restrict__ praw,
    const float* __restrict__ acc, const float* __restrict__ bp,
    const float* __restrict__ bi, float* __restrict__ out)
{
    __shared__ float sm[2201];
    __shared__ float sU[5];
    const int tid = threadIdx.x;

    float* sPr = sm;          // 1600
    float* sSS = sm + 1600;   // 200
    float* M1  = sm + 1800;   // 200
    float* sA  = sm + 2000;   // 25

    for (int t = tid; t < NPTS * 5; t += 256) sSS[t] = S[t];
    const float psoff = acc[A_SOFF] + bp[1];
    const float psdg  = acc[A_SDG]  + bp[0];
    for (int p = tid; p < NN; p += 256) {
        const int a = p / NPTS, b = p % NPTS;
        float v;
        if (a == b) v = acc[PDG + a] + psdg;
        else        v = praw[p] + acc[PVA + a] + acc[PVB + b] + psoff;
        sPr[p] = v;
    }
    __syncthreads();
    if (tid < 200) {
        const int c = tid / NPTS, b = tid % NPTS;
        float s = 0.f;
        for (int a = 0; a < NPTS; ++a) s += sSS[a * 5 + c] * sPr[a * NPTS + b];
        M1[c * NPTS + b] = s;
    }
    __syncthreads();
    if (tid < 25) {
        const int c = tid / 5, d = tid % 5;
        float s = 0.f;
        for (int b = 0; b < NPTS; ++b) s += M1[c * NPTS + b] * sSS[b * 5 + d];
        sA[tid] = s;
    }
    __syncthreads();

    if (tid == 0) {
        const float isc = acc[A_ISC] + bi[0];
        float A[5][5], V[5][5];
        // numpy eigh semantics: lower triangle mirrored
#pragma unroll
        for (int c = 0; c < 5; ++c)
#pragma unroll
            for (int d = 0; d < 5; ++d)
                A[c][d] = (c >= d) ? sA[c * 5 + d] : sA[d * 5 + c];
#pragma unroll
        for (int c = 0; c < 5; ++c) A[c][c] += isc;
#pragma unroll
        for (int c = 0; c < 5; ++c)
#pragma unroll
            for (int d = 0; d < 5; ++d) V[c][d] = (c == d) ? 1.f : 0.f;

        float dscale = 1.f;
#pragma unroll
        for (int c = 0; c < 5; ++c) dscale += A[c][c] * A[c][c];
        for (int sweep = 0; sweep < 15; ++sweep) {
            float off = 0.f;
#pragma unroll
            for (int p = 0; p < 4; ++p)
#pragma unroll
                for (int q = p + 1; q < 5; ++q) off += A[p][q] * A[p][q];
            if (off < 1e-11f * dscale) break;
#pragma unroll
            for (int p = 0; p < 4; ++p) {
#pragma unroll
                for (int q = p + 1; q < 5; ++q) {
                    const float apq = A[p][q];
                    if (fabsf(apq) < 1e-30f) continue;
                    const float theta = (A[q][q] - A[p][p]) / (2.f * apq);
                    const float t = (theta >= 0.f ? 1.f : -1.f) / (fabsf(theta) + sqrtf(theta * theta + 1.f));
                    const float cth = 1.f / sqrtf(t * t + 1.f);
                    const float sth = t * cth;
#pragma unroll
                    for (int k = 0; k < 5; ++k) {
                        const float akp = A[k][p], akq = A[k][q];
                        A[k][p] = cth * akp - sth * akq;
                        A[k][q] = sth * akp + cth * akq;
                    }
#pragma unroll
                    for (int k = 0; k < 5; ++k) {
                        const float apk = A[p][k], aqk = A[q][k];
                        A[p][k] = cth * apk - sth * aqk;
                        A[q][k] = sth * apk + cth * aqk;
                    }
#pragma unroll
                    for (int k = 0; k < 5; ++k) {
                        const float vkp = V[k][p], vkq = V[k][q];
                        V[k][p] = cth * vkp - sth * vkq;
                        V[k][q] = sth * vkp + cth * vkq;
                    }
                }
            }
        }
        int best = 0;
#pragma unroll
        for (int k = 1; k < 5; ++k) if (A[k][k] > A[best][best]) best = k;
        float u[5];
#pragma unroll
        for (int k = 0; k < 5; ++k) u[k] = V[k][best];
        int jm = 0; float am = fabsf(u[0]);
#pragma unroll
        for (int k = 1; k < 5; ++k) if (fabsf(u[k]) > am) { am = fabsf(u[k]); jm = k; }
        if (u[jm] < 0.f) {
#pragma unroll
            for (int k = 0; k < 5; ++k) u[k] = -u[k];
        }
#pragma unroll
        for (int k = 0; k < 5; ++k) sU[k] = u[k];
    }
    __syncthreads();
    if (tid < NPTS) {
        float s = 0.f;
#pragma unroll
        for (int k = 0; k < 5; ++k) s += sSS[tid * 5 + k] * sU[k];
        out[tid] = s;
    }
}

extern "C" void kernel_launch(void* const* d_in, const int* in_sizes, int n_in,
                              void* d_out, int out_size, void* d_ws, size_t ws_size,
                              hipStream_t stream) {
    const float* S  = (const float*)d_in[0];
    // d_in[1..3] basis tensors: unused (structure derived analytically)
    const float* W0 = (const float*)d_in[4];
    const float* b0 = (const float*)d_in[5];
    const float* Wh = (const float*)d_in[6];
    const float* bh = (const float*)d_in[7];
    const float* Wp = (const float*)d_in[8];
    const float* bp = (const float*)d_in[9];
    const float* Wi = (const float*)d_in[10];
    const float* bi = (const float*)d_in[11];
    float* outf = (float*)d_out;
    float* ws = (float*)d_ws;
    if (ws_size < (size_t)WS_TOTAL * sizeof(float)) return;

    float* XTA  = ws + WS_XTA;
    float* XTB  = ws + WS_XTB;
    float* stA  = ws + WS_STA;
    float* cm0  = ws + WS_CM0;
    float* cm1  = ws + WS_CM1;
    float* vt1  = ws + WS_VT1;
    float* vt2  = ws + WS_VT2;
    float* praw = ws + WS_PRAW;
    float* T1   = ws + WS_T1;
    float* acc  = ws + WS_ACC;

    k_l0c<<<WID, 256, 0, stream>>>(S, W0, b0, Wh, XTA, stA, cm0, cm1, T1, acc);
    k_sv1<<<41, 256, 0, stream>>>(stA, cm0, bh, vt1);
    k_hid1<<<390, 256, 0, stream>>>(XTA, vt1, cm0, XTB, T1);
    k_sv2<<<41, 256, 0, stream>>>(XTB, T1, cm1, bh + 2 * WID, vt2);
    k_hid2<<<390, 256, 0, stream>>>(XTB, vt2, cm1, Wp, Wi, praw, acc);
    k_final<<<1, 256, 0, stream>>>(S, praw, acc, bp, bi, outf);
}